// Round 6
// baseline (124.898 us; speedup 1.0000x reference)
//
#include <hip/hip_runtime.h>
#include <hip/hip_bf16.h>
#include <math.h>

// Problem dims (fixed by reference): B=64, N=32, S=1024, D=128
#define NB 64
#define NTOK 32
#define NS 1024
#define ND 128

typedef __attribute__((ext_vector_type(8))) short short8;  // 8 x bf16
typedef __attribute__((ext_vector_type(4))) float f32x4;

__device__ __forceinline__ unsigned short f2bf(float x) {
    unsigned int u = __builtin_bit_cast(unsigned int, x);
    u += 0x7fffu + ((u >> 16) & 1u);  // round-to-nearest-even
    return (unsigned short)(u >> 16);
}

__device__ __forceinline__ short8 cvt8(float4 a, float4 b) {
    float f[8] = {a.x, a.y, a.z, a.w, b.x, b.y, b.z, b.w};
    short8 r;
#pragma unroll
    for (int j = 0; j < 8; ++j) r[j] = (short)f2bf(f[j]);
    return r;
}

// Fragment map (validated rounds 2-5): a 16-row x 128-col tile is stored as
// [ks(4)][lane(64)][8]: lane l holds row (l&15), cols ks*32 + 8*(l>>4) + j.
// Slot s = ks*64+l  <->  fp32 element (row = s&15, colbase = (s>>6)*32 + ((s>>4)&3)*8).

// Fused maxsim: conversion + staging + MFMA in one kernel (no df/nf round-trip).
// Grid (c=64, bg=8, sh=4); linear id = c + 64*bg + 512*sh -> XCD = c%8 (all 32
// blocks sharing doc slice c are co-XCD). Block: 4 waves, 8 b's (2 per wave).
// Stages 256 doc rows (64 KB, fp32->bf16 fused, slot-linear ds_write) ONCE,
// one barrier, then 16 s-subtiles of pure MFMA+fmax with no further barriers.
// 2 blocks/CU (VGPR 128, LDS 64KB): one stages while the other computes.
__global__ __launch_bounds__(256, 2) void maxsim_fused(const float* __restrict__ qe,
                                                       const float* __restrict__ dc,
                                                       const float* __restrict__ ng,
                                                       float* __restrict__ score_part,
                                                       float* __restrict__ neg_part) {
    int c = blockIdx.x;
    int bg = blockIdx.y;
    int sh = blockIdx.z;
    int t = threadIdx.x;
    int w = t >> 6, l = t & 63;
    int b0 = bg * 8 + w * 2;  // this wave: b0, b0+1

    __shared__ alignas(16) short lds[16 * 2048];  // 16 tiles = 256 doc rows, 64 KB
    f32x4 zero = {0.f, 0.f, 0.f, 0.f};

    // ---- q fragments, fp32 -> bf16 on the fly: qa[bb][m][ks] (64 VGPR) ----
    short8 qa[2][2][4];
#pragma unroll
    for (int bb = 0; bb < 2; ++bb)
#pragma unroll
        for (int m = 0; m < 2; ++m)
#pragma unroll
            for (int ks = 0; ks < 4; ++ks) {
                const float* s =
                    qe + ((b0 + bb) * 32 + m * 16 + (l & 15)) * ND + ks * 32 + 8 * (l >> 4);
                qa[bb][m][ks] = cvt8(((const float4*)s)[0], ((const float4*)s)[1]);
            }

    // ---- stage 256 doc rows with fused convert; thread t owns slot t of each
    // tile -> ds_write is linear (conflict-free). fp32 read: row t&15 (512B
    // stride), 32B per lane -- L2/L3 backed. ----
    const float* dbase = dc + (c * NS + sh * 256) * ND;
    int roff = (t & 15) * ND + (t >> 6) * 32 + ((t >> 4) & 3) * 8;
#pragma unroll
    for (int T = 0; T < 16; T += 4) {
        float4 fa[4], fb[4];
#pragma unroll
        for (int i = 0; i < 4; ++i) {
            const float* s = dbase + (T + i) * 2048 + roff;
            fa[i] = ((const float4*)s)[0];
            fb[i] = ((const float4*)s)[1];
        }
#pragma unroll
        for (int i = 0; i < 4; ++i)
            *(short8*)(&lds[(T + i) * 2048 + t * 8]) = cvt8(fa[i], fb[i]);
    }

    // ---- fused neg partial (sh==0): tile (b, s-chunk c) of q[b]·neg[b] ----
    if (sh == 0) {
#pragma unroll
        for (int bb = 0; bb < 2; ++bb) {
            const float* nt =
                ng + (((b0 + bb) * 64 + c) * 16 + (l & 15)) * ND + 8 * (l >> 4);
            short8 nb[4];
#pragma unroll
            for (int ks = 0; ks < 4; ++ks) {
                const float* s = nt + ks * 32;
                nb[ks] = cvt8(((const float4*)s)[0], ((const float4*)s)[1]);
            }
#pragma unroll
            for (int m = 0; m < 2; ++m) {
                f32x4 acc = zero;
#pragma unroll
                for (int ks = 0; ks < 4; ++ks)
                    acc = __builtin_amdgcn_mfma_f32_16x16x32_bf16(qa[bb][m][ks], nb[ks], acc, 0, 0, 0);
#pragma unroll
                for (int r = 0; r < 4; ++r) {  // rowmax over s within 16-lane group
                    float v = acc[r];
                    v = fmaxf(v, __shfl_xor(v, 1));
                    v = fmaxf(v, __shfl_xor(v, 2));
                    v = fmaxf(v, __shfl_xor(v, 4));
                    v = fmaxf(v, __shfl_xor(v, 8));
                    if ((l & 15) == 0)
                        neg_part[(c * 64 + (b0 + bb)) * 32 + m * 16 + (l >> 4) * 4 + r] = v;
                }
            }
        }
    }

    __syncthreads();  // the only barrier: LDS staging published

    // ---- main: 16 s-subtiles, no barriers, MFMA-dense ----
    f32x4 vmax[2][2];
#pragma unroll
    for (int bb = 0; bb < 2; ++bb)
#pragma unroll
        for (int m = 0; m < 2; ++m)
#pragma unroll
            for (int r = 0; r < 4; ++r) vmax[bb][m][r] = -INFINITY;

    for (int ss = 0; ss < 16; ++ss) {
        short8 bf[4];
#pragma unroll
        for (int ks = 0; ks < 4; ++ks)
            bf[ks] = *(const short8*)(&lds[ss * 2048 + ks * 512 + l * 8]);
#pragma unroll
        for (int bb = 0; bb < 2; ++bb)
#pragma unroll
            for (int m = 0; m < 2; ++m) {
                f32x4 acc = zero;
#pragma unroll
                for (int ks = 0; ks < 4; ++ks)
                    acc = __builtin_amdgcn_mfma_f32_16x16x32_bf16(qa[bb][m][ks], bf[ks], acc, 0, 0, 0);
#pragma unroll
                for (int r = 0; r < 4; ++r)
                    vmax[bb][m][r] = fmaxf(vmax[bb][m][r], acc[r]);
            }
    }

    // per-n rowmax partial -> score_part[((sh*64 + c)*64 + b)*32 + n]
#pragma unroll
    for (int bb = 0; bb < 2; ++bb)
#pragma unroll
        for (int m = 0; m < 2; ++m)
#pragma unroll
            for (int r = 0; r < 4; ++r) {
                float v = vmax[bb][m][r];
                v = fmaxf(v, __shfl_xor(v, 1));
                v = fmaxf(v, __shfl_xor(v, 2));
                v = fmaxf(v, __shfl_xor(v, 4));
                v = fmaxf(v, __shfl_xor(v, 8));
                if ((l & 15) == 0)
                    score_part[((sh * 64 + c) * 64 + (b0 + bb)) * 32 + m * 16 + (l >> 4) * 4 + r] = v;
            }
}

// Per-b reduction: combine 4 sh-quarters -> scores[b][c] (c = lane), reduce
// neg_part over c, then CE + softplus -> bloss[b]. 64 blocks x 64 threads.
__global__ __launch_bounds__(64) void reduce_b(const float* __restrict__ score_part,
                                               const float* __restrict__ neg_part,
                                               const int* __restrict__ offp,
                                               float* __restrict__ bloss) {
    int b = blockIdx.x;
    int c = threadIdx.x;  // one wave
    const int PSTRIDE = 64 * 64 * 32;
    float s = 0.f;
#pragma unroll
    for (int j = 0; j < 8; ++j) {
        float4 v0 = ((const float4*)(score_part + 0 * PSTRIDE + (c * 64 + b) * 32))[j];
        float4 v1 = ((const float4*)(score_part + 1 * PSTRIDE + (c * 64 + b) * 32))[j];
        float4 v2 = ((const float4*)(score_part + 2 * PSTRIDE + (c * 64 + b) * 32))[j];
        float4 v3 = ((const float4*)(score_part + 3 * PSTRIDE + (c * 64 + b) * 32))[j];
        s += fmaxf(fmaxf(v0.x, v1.x), fmaxf(v2.x, v3.x));
        s += fmaxf(fmaxf(v0.y, v1.y), fmaxf(v2.y, v3.y));
        s += fmaxf(fmaxf(v0.z, v1.z), fmaxf(v2.z, v3.z));
        s += fmaxf(fmaxf(v0.w, v1.w), fmaxf(v2.w, v3.w));
    }
    // neg: elementwise max over c of neg_part[c][b][n], then sum over n
    float v[32];
    {
        const float4* np = (const float4*)(neg_part + (c * 64 + b) * 32);
#pragma unroll
        for (int j = 0; j < 8; ++j) {
            float4 a = np[j];
            v[j * 4] = a.x; v[j * 4 + 1] = a.y; v[j * 4 + 2] = a.z; v[j * 4 + 3] = a.w;
        }
    }
#pragma unroll
    for (int off = 1; off < 64; off <<= 1)
#pragma unroll
        for (int j = 0; j < 32; ++j) v[j] = fmaxf(v[j], __shfl_xor(v[j], off));
    float negs = 0.f;
#pragma unroll
    for (int j = 0; j < 32; ++j) negs += v[j];

    const float invT = 50.0f;
    float m = s;
#pragma unroll
    for (int off = 1; off < 64; off <<= 1) m = fmaxf(m, __shfl_xor(m, off));
    float e = expf((s - m) * invT);
#pragma unroll
    for (int off = 1; off < 64; off <<= 1) e += __shfl_xor(e, off);
    float lse = m * invT + logf(e);
    int label = offp[0] + b;
    label = label < 0 ? 0 : (label > 63 ? 63 : label);
    float slabel = __shfl(s, label);
    float pos = __shfl(s, b);
    if (c == 0) {
        float x = (negs - pos) * invT;
        float sp = fmaxf(x, 0.f) + log1pf(expf(-fabsf(x)));
        bloss[b] = sp + lse - slabel * invT;
    }
}

__global__ __launch_bounds__(64) void final_sum(const float* __restrict__ bloss,
                                                float* __restrict__ out) {
    float v = bloss[threadIdx.x];
#pragma unroll
    for (int off = 1; off < 64; off <<= 1) v += __shfl_xor(v, off);
    if (threadIdx.x == 0) out[0] = v * (0.5f / 64.f);
}

extern "C" void kernel_launch(void* const* d_in, const int* in_sizes, int n_in,
                              void* d_out, int out_size, void* d_ws, size_t ws_size,
                              hipStream_t stream) {
    const float* q = (const float*)d_in[0];
    const float* dc = (const float*)d_in[1];
    const float* ng = (const float*)d_in[2];
    const int* offp = (const int*)d_in[3];
    float* out = (float*)d_out;

    // ws: neg_part 512KB @0 | score_part 2MB @0x80000 | bloss @0x280000
    char* ws = (char*)d_ws;
    float* neg_part = (float*)(ws);
    float* score_part = (float*)(ws + 0x80000);
    float* bloss = (float*)(ws + 0x280000);
    if (ws_size < 0x280200) return;

    maxsim_fused<<<dim3(64, 8, 4), 256, 0, stream>>>(q, dc, ng, score_part, neg_part);
    reduce_b<<<64, 64, 0, stream>>>(score_part, neg_part, offp, bloss);
    final_sum<<<1, 64, 0, stream>>>(bloss, out);
}

// Round 7
// 61.831 us; speedup vs baseline: 2.0200x; 2.0200x over previous
//
#include <hip/hip_runtime.h>
#include <hip/hip_bf16.h>
#include <math.h>

// Problem dims (fixed by reference): B=64, N=32, S=1024, D=128
#define NB 64
#define NTOK 32
#define NS 1024
#define ND 128

typedef __attribute__((ext_vector_type(8))) short short8;  // 8 x bf16
typedef __attribute__((ext_vector_type(4))) float f32x4;

// 8 fp32 -> 8 bf16 via v_cvt_pk_bf16_f32 (1 instr / 2 floats). All of q, doc,
// neg go through this SAME function, so any pairing-order quirk cancels in the
// MFMA dot product (A and B share the k-map).
__device__ __forceinline__ short8 cvt8(float4 a, float4 b) {
    union { unsigned int u[4]; short8 s; } r;
    asm("v_cvt_pk_bf16_f32 %0, %1, %2" : "=v"(r.u[0]) : "v"(a.x), "v"(a.y));
    asm("v_cvt_pk_bf16_f32 %0, %1, %2" : "=v"(r.u[1]) : "v"(a.z), "v"(a.w));
    asm("v_cvt_pk_bf16_f32 %0, %1, %2" : "=v"(r.u[2]) : "v"(b.x), "v"(b.y));
    asm("v_cvt_pk_bf16_f32 %0, %1, %2" : "=v"(r.u[3]) : "v"(b.z), "v"(b.w));
    return r.s;
}

// Fragment layout per 16x128 tile: [ks(4)][lane(64)] short8; lane l = row (l&15),
// k = ks*32 + 8*(l>>4) + j. LDS slots are XOR-swizzled: phys = slot ^ key,
// key(slot) = ((slot>>6)&1)<<2 | ((slot>>4)&3). Write side (row=t>>4, g=t&15):
// slot = (g>>2)*64+(g&3)*16+row, key = g&7 -> groups (row^(g&7))%8 uniform (8
// lanes/group). Read side (ks,l): key = ((ks&1)<<2)|(l>>4) -> uniform. Both
// conflict-free for b128 (256 dwords / 32 banks = 8 cy min achieved).

// Fused kernel: fp32 read (coalesced) + bf16 convert + swizzled LDS staging +
// MFMA maxsim + distributed neg partials. Grid (c=64, bg=8, sh=2): linear id
// = c + 64*bg + 512*sh -> XCD = c%8, all 16 blocks sharing slice c co-XCD.
// Block: 4 waves, 2 b's each; chunk = 32 doc rows (2 tiles), 16 chunks,
// double-buffered 2x8KB LDS, ONE barrier per chunk; prefetch 4xfloat4 (16 VGPR).
__global__ __launch_bounds__(256, 2) void maxsim_fused(const float* __restrict__ qe,
                                                       const float* __restrict__ dc,
                                                       const float* __restrict__ ng,
                                                       float* __restrict__ score_part,
                                                       float* __restrict__ neg_part) {
    int c = blockIdx.x;
    int bg = blockIdx.y;
    int sh = blockIdx.z;
    int t = threadIdx.x;
    int w = t >> 6, l = t & 63;
    int b0 = bg * 8 + w * 2;  // this wave: b0, b0+1

    __shared__ alignas(16) short lds[2][4096];  // 2 x 8KB (2 tiles each)
    f32x4 zero = {0.f, 0.f, 0.f, 0.f};

    // staging role: thread t covers (row = t>>4, cols 8g..8g+7), tiles T=0,1
    int row = t >> 4, g = t & 15;
    int slotw = (((g >> 2) * 64 + (g & 3) * 16 + row) ^ (g & 7));  // swizzled
    const float* src0 = dc + ((size_t)c * NS + (size_t)sh * 512 + row) * ND + g * 8;

    float4 pa[2], pb[2];
    // issue chunk-0 loads immediately (latency hidden under qa/neg work)
#pragma unroll
    for (int T = 0; T < 2; ++T) {
        const float* s = src0 + T * 16 * ND;
        pa[T] = ((const float4*)s)[0];
        pb[T] = ((const float4*)s)[1];
    }

    // q fragments fp32->bf16 on the fly: qa[bb][m][ks] (64 VGPR)
    short8 qa[2][2][4];
#pragma unroll
    for (int bb = 0; bb < 2; ++bb)
#pragma unroll
        for (int m = 0; m < 2; ++m)
#pragma unroll
            for (int ks = 0; ks < 4; ++ks) {
                const float* s =
                    qe + ((b0 + bb) * 32 + m * 16 + (l & 15)) * ND + ks * 32 + 8 * (l >> 4);
                qa[bb][m][ks] = cvt8(((const float4*)s)[0], ((const float4*)s)[1]);
            }

    if (sh == 0) {  // fused neg partial: tile (b, s-chunk c) of q[b]·neg[b]
#pragma unroll
        for (int bb = 0; bb < 2; ++bb) {
            const float* nt =
                ng + (((b0 + bb) * 64 + c) * 16 + (l & 15)) * ND + 8 * (l >> 4);
            short8 nb[4];
#pragma unroll
            for (int ks = 0; ks < 4; ++ks) {
                const float* s = nt + ks * 32;
                nb[ks] = cvt8(((const float4*)s)[0], ((const float4*)s)[1]);
            }
#pragma unroll
            for (int m = 0; m < 2; ++m) {
                f32x4 acc = zero;
#pragma unroll
                for (int ks = 0; ks < 4; ++ks)
                    acc = __builtin_amdgcn_mfma_f32_16x16x32_bf16(qa[bb][m][ks], nb[ks], acc, 0, 0, 0);
#pragma unroll
                for (int r = 0; r < 4; ++r) {
                    float v = acc[r];
                    v = fmaxf(v, __shfl_xor(v, 1));
                    v = fmaxf(v, __shfl_xor(v, 2));
                    v = fmaxf(v, __shfl_xor(v, 4));
                    v = fmaxf(v, __shfl_xor(v, 8));
                    if ((l & 15) == 0)
                        neg_part[(c * 64 + (b0 + bb)) * 32 + m * 16 + (l >> 4) * 4 + r] = v;
                }
            }
        }
    }

    // write chunk 0 (swizzled), publish
#pragma unroll
    for (int T = 0; T < 2; ++T)
        *(short8*)(&lds[0][(T * 256 + slotw) * 8]) = cvt8(pa[T], pb[T]);
    __syncthreads();

    f32x4 vmax[2][2];
#pragma unroll
    for (int bb = 0; bb < 2; ++bb)
#pragma unroll
        for (int m = 0; m < 2; ++m)
#pragma unroll
            for (int r = 0; r < 4; ++r) vmax[bb][m][r] = -INFINITY;

#define COMPUTE(P)                                                                      \
    _Pragma("unroll") for (int ss = 0; ss < 2; ++ss) {                                  \
        short8 bf[4];                                                                   \
        _Pragma("unroll") for (int ks = 0; ks < 4; ++ks) {                              \
            int rs = (ks * 64 + l) ^ (((ks & 1) << 2) | (l >> 4));                      \
            bf[ks] = *(const short8*)(&lds[P][(ss * 256 + rs) * 8]);                    \
        }                                                                               \
        _Pragma("unroll") for (int bb = 0; bb < 2; ++bb)                                \
            _Pragma("unroll") for (int m = 0; m < 2; ++m) {                             \
                f32x4 acc = zero;                                                       \
                _Pragma("unroll") for (int ks = 0; ks < 4; ++ks)                        \
                    acc = __builtin_amdgcn_mfma_f32_16x16x32_bf16(qa[bb][m][ks],        \
                                                                  bf[ks], acc, 0, 0, 0);\
                _Pragma("unroll") for (int r = 0; r < 4; ++r)                           \
                    vmax[bb][m][r] = fmaxf(vmax[bb][m][r], acc[r]);                     \
            }                                                                           \
    }

    // STEP(ch, read-buf, write-buf): prefetch ch+1, compute ch, stage ch+1, barrier
#define STEP(CH, PRD, PWR)                                                              \
    if ((CH) + 1 < 16) {                                                                \
        _Pragma("unroll") for (int T = 0; T < 2; ++T) {                                 \
            const float* s = src0 + ((CH) + 1) * (32 * ND) + T * 16 * ND;               \
            pa[T] = ((const float4*)s)[0];                                              \
            pb[T] = ((const float4*)s)[1];                                              \
        }                                                                               \
    }                                                                                   \
    COMPUTE(PRD);                                                                       \
    if ((CH) + 1 < 16) {                                                                \
        _Pragma("unroll") for (int T = 0; T < 2; ++T)                                   \
            *(short8*)(&lds[PWR][(T * 256 + slotw) * 8]) = cvt8(pa[T], pb[T]);          \
    }                                                                                   \
    __syncthreads();

    for (int it = 0; it < 8; ++it) {
        int ch0 = it * 2;
        STEP(ch0, 0, 1);
        STEP(ch0 + 1, 1, 0);
    }
#undef STEP
#undef COMPUTE

    // per-n rowmax partial -> score_part[((sh*64 + c)*64 + b)*32 + n]
#pragma unroll
    for (int bb = 0; bb < 2; ++bb)
#pragma unroll
        for (int m = 0; m < 2; ++m)
#pragma unroll
            for (int r = 0; r < 4; ++r) {
                float v = vmax[bb][m][r];
                v = fmaxf(v, __shfl_xor(v, 1));
                v = fmaxf(v, __shfl_xor(v, 2));
                v = fmaxf(v, __shfl_xor(v, 4));
                v = fmaxf(v, __shfl_xor(v, 8));
                if ((l & 15) == 0)
                    score_part[((sh * 64 + c) * 64 + (b0 + bb)) * 32 + m * 16 + (l >> 4) * 4 + r] = v;
            }
}

// Per-b reduction: combine sh-halves -> scores[b][c] (c = lane), reduce
// neg_part over c, then CE + softplus -> bloss[b]. 64 blocks x 64 threads.
__global__ __launch_bounds__(64) void reduce_b(const float* __restrict__ score_part,
                                               const float* __restrict__ neg_part,
                                               const int* __restrict__ offp,
                                               float* __restrict__ bloss) {
    int b = blockIdx.x;
    int c = threadIdx.x;  // one wave
    const float4* p0 = (const float4*)(score_part + (c * 64 + b) * 32);
    const float4* p1 = (const float4*)(score_part + 64 * 64 * 32 + (c * 64 + b) * 32);
    float s = 0.f;
#pragma unroll
    for (int j = 0; j < 8; ++j) {
        float4 a = p0[j], q = p1[j];
        s += fmaxf(a.x, q.x) + fmaxf(a.y, q.y) + fmaxf(a.z, q.z) + fmaxf(a.w, q.w);
    }
    // neg: elementwise max over c of neg_part[c][b][n], then sum over n
    float v[32];
    {
        const float4* np = (const float4*)(neg_part + (c * 64 + b) * 32);
#pragma unroll
        for (int j = 0; j < 8; ++j) {
            float4 a = np[j];
            v[j * 4] = a.x; v[j * 4 + 1] = a.y; v[j * 4 + 2] = a.z; v[j * 4 + 3] = a.w;
        }
    }
#pragma unroll
    for (int off = 1; off < 64; off <<= 1)
#pragma unroll
        for (int j = 0; j < 32; ++j) v[j] = fmaxf(v[j], __shfl_xor(v[j], off));
    float negs = 0.f;
#pragma unroll
    for (int j = 0; j < 32; ++j) negs += v[j];

    const float invT = 50.0f;
    float m = s;
#pragma unroll
    for (int off = 1; off < 64; off <<= 1) m = fmaxf(m, __shfl_xor(m, off));
    float e = expf((s - m) * invT);
#pragma unroll
    for (int off = 1; off < 64; off <<= 1) e += __shfl_xor(e, off);
    float lse = m * invT + logf(e);
    int label = offp[0] + b;
    label = label < 0 ? 0 : (label > 63 ? 63 : label);
    float slabel = __shfl(s, label);
    float pos = __shfl(s, b);
    if (c == 0) {
        float x = (negs - pos) * invT;
        float sp = fmaxf(x, 0.f) + log1pf(expf(-fabsf(x)));
        bloss[b] = sp + lse - slabel * invT;
    }
}

__global__ __launch_bounds__(64) void final_sum(const float* __restrict__ bloss,
                                                float* __restrict__ out) {
    float v = bloss[threadIdx.x];
#pragma unroll
    for (int off = 1; off < 64; off <<= 1) v += __shfl_xor(v, off);
    if (threadIdx.x == 0) out[0] = v * (0.5f / 64.f);
}

extern "C" void kernel_launch(void* const* d_in, const int* in_sizes, int n_in,
                              void* d_out, int out_size, void* d_ws, size_t ws_size,
                              hipStream_t stream) {
    const float* q = (const float*)d_in[0];
    const float* dc = (const float*)d_in[1];
    const float* ng = (const float*)d_in[2];
    const int* offp = (const int*)d_in[3];
    float* out = (float*)d_out;

    // ws: neg_part 512KB @0 | score_part 1MB @0x80000 | bloss @0x180000
    char* ws = (char*)d_ws;
    float* neg_part = (float*)(ws);
    float* score_part = (float*)(ws + 0x80000);
    float* bloss = (float*)(ws + 0x180000);
    if (ws_size < 0x180200) return;

    maxsim_fused<<<dim3(64, 8, 2), 256, 0, stream>>>(q, dc, ng, score_part, neg_part);
    reduce_b<<<64, 64, 0, stream>>>(score_part, neg_part, offp, bloss);
    final_sum<<<1, 64, 0, stream>>>(bloss, out);
}